// Round 12
// baseline (41.741 us; speedup 1.0000x reference)
//
#include <hip/hip_runtime.h>
#include <math.h>

constexpr int Bb = 4, Cc = 64, Hh = 256, Ww = 256;
constexpr int RR = 4;            // output rows per block
constexpr int CS = 4;            // channel split (16 ch per block)
constexpr int NSTRIP = Hh / RR;  // 64
constexpr int NPX = Bb * Hh * Ww;       // 262144 output pixels
constexpr int NPX4 = NPX / 4;           // 65536 float4s

#define LOG2E 1.44269504088896340736f
#define LN2   0.69314718055994530942f

__device__ __forceinline__ unsigned int fenc(float f) {
  unsigned int u = __float_as_uint(f);
  return (u & 0x80000000u) ? ~u : (u | 0x80000000u);
}
__device__ __forceinline__ float fdec(unsigned int k) {
  return __uint_as_float((k & 0x80000000u) ? (k ^ 0x80000000u) : ~k);
}

// entropy = ln(s) - ws/s, s = 3x3 box of e^v, ws = 3x3 box of v*e^v
// (shift-invariant softmax entropy; N(0,1) inputs so e^v safe in fp32).
// Normalization is affine-invariant, so raw channel sums are normalized.
//
// Grid: b(4) x strip(64) x cs(4) = 1024 blocks, block (64,8) -> 8192 waves.
// Each block: RR=4 output rows x 16 channels (2 per ty, rolled cc loop).
// Block 0 also re-zeroes the 8 sync words for the finish kernel (kernel
// boundary makes this visible; avoids any memset dispatch).
//   DST=0: non-atomic store of channel-quarter partial into pw[cs][...]
//   DST=1: atomicAdd into e (fallback; e pre-zeroed)
// NOTE: plain __launch_bounds__(512) only — min-waves hints spill (r6/r7).
template <int DST>
__global__ __launch_bounds__(512) void entropy_kernel(const float* __restrict__ x,
                                                      float* __restrict__ out,
                                                      unsigned int* __restrict__ sync) {
  const int bx = blockIdx.x;
  if (DST == 0 && bx == 0 && threadIdx.x < 8 && threadIdx.y == 0)
    sync[threadIdx.x] = 0u;

  const int cs = bx & 3;
  const int strip = (bx >> 2) & (NSTRIP - 1);
  const int b = bx >> 8;
  const int r0 = strip * RR;
  const int tx = threadIdx.x;   // 0..63
  const int ty = threadIdx.y;   // 0..7
  const int w0 = tx * 4;

  const size_t planeStride = (size_t)Hh * Ww;
  const float* xb = x + ((size_t)b * Cc + cs * 16 + ty * 2) * planeStride + w0;

  float acc[RR][4];
#pragma unroll
  for (int o = 0; o < RR; ++o)
#pragma unroll
    for (int i = 0; i < 4; ++i) acc[o][i] = 0.f;

#pragma unroll 1
  for (int cc = 0; cc < 2; ++cc) {
    const float* plane = xb + (size_t)cc * planeStride;

    // Preload the RR+2 = 6 strip rows (6 outstanding dwordx4 loads).
    float4 v[RR + 2];
#pragma unroll
    for (int j = 0; j < RR + 2; ++j) {
      const int row = r0 - 1 + j;
      if (row >= 0 && row < Hh)
        v[j] = *reinterpret_cast<const float4*>(plane + (size_t)row * Ww);
      else
        v[j] = make_float4(0.f, 0.f, 0.f, 0.f);
    }

    float ha[3][4], hb[3][4];
#pragma unroll
    for (int j = 0; j < RR + 2; ++j) {
      const float* vp = &v[j].x;
      float a[4], bb4[4];
#pragma unroll
      for (int i = 0; i < 4; ++i) {
        float t = __builtin_amdgcn_exp2f(vp[i] * LOG2E);  // e^v
        a[i] = t;
        bb4[i] = vp[i] * t;                               // v * e^v
      }
      float la = __shfl_up(a[3], 1, 64);
      float lb = __shfl_up(bb4[3], 1, 64);
      float ra = __shfl_down(a[0], 1, 64);
      float rb = __shfl_down(bb4[0], 1, 64);
      la = (tx == 0) ? 1.f : la;   lb = (tx == 0) ? 0.f : lb;
      ra = (tx == 63) ? 1.f : ra;  rb = (tx == 63) ? 0.f : rb;
      const int s0 = j % 3;  // compile-time (loop unrolled)
      ha[s0][0] = la + a[0] + a[1];
      ha[s0][1] = a[0] + a[1] + a[2];
      ha[s0][2] = a[1] + a[2] + a[3];
      ha[s0][3] = a[2] + a[3] + ra;
      hb[s0][0] = lb + bb4[0] + bb4[1];
      hb[s0][1] = bb4[0] + bb4[1] + bb4[2];
      hb[s0][2] = bb4[1] + bb4[2] + bb4[3];
      hb[s0][3] = bb4[2] + bb4[3] + rb;
      if (j >= 2) {
        const int orow = j - 2;
#pragma unroll
        for (int i = 0; i < 4; ++i) {
          float s = ha[0][i] + ha[1][i] + ha[2][i];
          float w = hb[0][i] + hb[1][i] + hb[2][i];
          acc[orow][i] += LN2 * __builtin_amdgcn_logf(s) -
                          w * __builtin_amdgcn_rcpf(s);
        }
      }
    }
  }

  // Reduce the 8 ty groups (32 KiB LDS).
  __shared__ float red[8][RR][4][64];
#pragma unroll
  for (int o = 0; o < RR; ++o)
#pragma unroll
    for (int i = 0; i < 4; ++i) red[ty][o][i][tx] = acc[o][i];
  __syncthreads();
  if (ty < RR) {
    const int o = ty;
    const size_t px = (size_t)(b * Hh + r0 + o) * Ww + w0;
    float vsum[4];
#pragma unroll
    for (int i = 0; i < 4; ++i) {
      float t = 0.f;
#pragma unroll
      for (int g = 0; g < 8; ++g) t += red[g][o][i][tx];
      vsum[i] = t;
    }
    if (DST == 0) {
      *reinterpret_cast<float4*>(out + (size_t)cs * NPX + px) =
          make_float4(vsum[0], vsum[1], vsum[2], vsum[3]);
    } else {
#pragma unroll
      for (int i = 0; i < 4; ++i) atomicAdd(out + px + i, vsum[i]);
    }
  }
}

// Fused finish: combine 4 partial planes (in registers), per-batch min/max
// via last-block reduction (threadfence pattern), then normalize and write
// the final output — one dispatch, no memsets, no e round-trip.
// Grid 256 blocks x 256 threads; batch b = bx>>6 (64 blocks each).
// pm: [256 min][256 max] block partials. stats: {mn,inv} per batch.
// sync: cnt[0..3], flag[4..7] — zeroed by entropy_kernel block 0.
__global__ __launch_bounds__(256) void finish_kernel(const float* __restrict__ pw,
                                                     float* __restrict__ e,
                                                     float* __restrict__ pm,
                                                     float* __restrict__ stats,
                                                     unsigned int* __restrict__ sync) {
  const int bx = blockIdx.x;
  const int b = bx >> 6;
  const int t = bx * 256 + threadIdx.x;

  float4 v0 = reinterpret_cast<const float4*>(pw)[t];
  float4 v1 = reinterpret_cast<const float4*>(pw + (size_t)NPX)[t];
  float4 v2 = reinterpret_cast<const float4*>(pw + 2 * (size_t)NPX)[t];
  float4 v3 = reinterpret_cast<const float4*>(pw + 3 * (size_t)NPX)[t];
  float4 v = make_float4(v0.x + v1.x + v2.x + v3.x, v0.y + v1.y + v2.y + v3.y,
                         v0.z + v1.z + v2.z + v3.z, v0.w + v1.w + v2.w + v3.w);

  // Block-level min/max.
  float mn = fminf(fminf(v.x, v.y), fminf(v.z, v.w));
  float mx = fmaxf(fmaxf(v.x, v.y), fmaxf(v.z, v.w));
#pragma unroll
  for (int off = 32; off > 0; off >>= 1) {
    mn = fminf(mn, __shfl_down(mn, off, 64));
    mx = fmaxf(mx, __shfl_down(mx, off, 64));
  }
  __shared__ float smn[4], smx[4];
  __shared__ int is_last;
  const int wave = threadIdx.x >> 6;
  if ((threadIdx.x & 63) == 0) { smn[wave] = mn; smx[wave] = mx; }
  __syncthreads();
  if (threadIdx.x == 0) {
    pm[bx]       = fminf(fminf(smn[0], smn[1]), fminf(smn[2], smn[3]));
    pm[256 + bx] = fmaxf(fmaxf(smx[0], smx[1]), fmaxf(smx[2], smx[3]));
    __threadfence();
    is_last = (atomicAdd(&sync[b], 1u) == 63u);
  }
  __syncthreads();
  if (is_last && threadIdx.x < 64) {
    __threadfence();  // acquire: other blocks' pm writes
    float rmn = pm[b * 64 + threadIdx.x];
    float rmx = pm[256 + b * 64 + threadIdx.x];
#pragma unroll
    for (int off = 32; off > 0; off >>= 1) {
      rmn = fminf(rmn, __shfl_down(rmn, off, 64));
      rmx = fmaxf(rmx, __shfl_down(rmx, off, 64));
    }
    if (threadIdx.x == 0) {
      stats[2 * b] = rmn;
      stats[2 * b + 1] = 1.0f / fmaxf(rmx - rmn, 1e-6f);
      __threadfence();
      atomicExch(&sync[4 + b], 1u);
    }
  }

  // Wait for this batch's stats, then normalize from registers.
  __shared__ float s_mn, s_inv;
  if (threadIdx.x == 0) {
    while (__hip_atomic_load(&sync[4 + b], __ATOMIC_ACQUIRE,
                             __HIP_MEMORY_SCOPE_AGENT) == 0u) {
      __builtin_amdgcn_s_sleep(2);
    }
    s_mn = stats[2 * b];
    s_inv = stats[2 * b + 1];
  }
  __syncthreads();
  const float mnb = s_mn, inv = s_inv;
  v.x = (v.x - mnb) * inv;
  v.y = (v.y - mnb) * inv;
  v.z = (v.z - mnb) * inv;
  v.w = (v.w - mnb) * inv;
  reinterpret_cast<float4*>(e)[t] = v;
}

// Fallback path kernels (atomics + memset) — used only if ws is tiny.
__global__ __launch_bounds__(256) void minmax_atomic(const float* __restrict__ e,
                                                     unsigned int* __restrict__ stats) {
  const int bx = blockIdx.x;
  const int b = bx >> 6;
  const float4 v = reinterpret_cast<const float4*>(
      e + (size_t)b * Hh * Ww + (bx & 63) * 1024)[threadIdx.x];
  float mn = fminf(fminf(v.x, v.y), fminf(v.z, v.w));
  float mx = fmaxf(fmaxf(v.x, v.y), fmaxf(v.z, v.w));
#pragma unroll
  for (int off = 32; off > 0; off >>= 1) {
    mn = fminf(mn, __shfl_down(mn, off, 64));
    mx = fmaxf(mx, __shfl_down(mx, off, 64));
  }
  __shared__ float smn[4], smx[4];
  const int wave = threadIdx.x >> 6;
  if ((threadIdx.x & 63) == 0) { smn[wave] = mn; smx[wave] = mx; }
  __syncthreads();
  if (threadIdx.x == 0) {
    atomicMin(&stats[b], fenc(fminf(fminf(smn[0], smn[1]), fminf(smn[2], smn[3]))));
    atomicMax(&stats[4 + b], fenc(fmaxf(fmaxf(smx[0], smx[1]), fmaxf(smx[2], smx[3]))));
  }
}

__global__ __launch_bounds__(256) void norm_atomic(float* __restrict__ e,
                                                   const unsigned int* __restrict__ stats) {
  const int t = blockIdx.x * 256 + threadIdx.x;
  const int b = t >> 14;
  const float mn = fdec(stats[b]);
  const float mx = fdec(stats[4 + b]);
  const float inv = 1.0f / fmaxf(mx - mn, 1e-6f);
  float4 v = reinterpret_cast<float4*>(e)[t];
  v.x = (v.x - mn) * inv;
  v.y = (v.y - mn) * inv;
  v.z = (v.z - mn) * inv;
  v.w = (v.w - mn) * inv;
  reinterpret_cast<float4*>(e)[t] = v;
}

extern "C" void kernel_launch(void* const* d_in, const int* in_sizes, int n_in,
                              void* d_out, int out_size, void* d_ws, size_t ws_size,
                              hipStream_t stream) {
  const float* x = (const float*)d_in[0];
  float* out = (float*)d_out;

  // ws layout: pw[CS*NPX] | pm[512] | stats[8] | sync[8]
  const size_t ws_needed = ((size_t)CS * NPX + 512 + 8 + 8) * sizeof(float);
  if (ws_size >= ws_needed) {
    float* pw = (float*)d_ws;
    float* pm = pw + (size_t)CS * NPX;
    float* stats = pm + 512;
    unsigned int* sync = (unsigned int*)(stats + 8);
    entropy_kernel<0><<<dim3(Bb * NSTRIP * CS), dim3(64, 8), 0, stream>>>(x, pw, sync);
    finish_kernel<<<dim3(NPX4 / 256), dim3(256), 0, stream>>>(pw, out, pm, stats, sync);
  } else {
    unsigned int* stats = (unsigned int*)d_ws;  // 8 uints
    hipMemsetAsync(out, 0, (size_t)NPX * sizeof(float), stream);
    hipMemsetAsync(stats, 0xFF, 4 * sizeof(unsigned int), stream);
    hipMemsetAsync(stats + 4, 0x00, 4 * sizeof(unsigned int), stream);
    entropy_kernel<1><<<dim3(Bb * NSTRIP * CS), dim3(64, 8), 0, stream>>>(x, out, nullptr);
    minmax_atomic<<<dim3(Bb * 64), dim3(256), 0, stream>>>(out, stats);
    norm_atomic<<<dim3(NPX4 / 256), dim3(256), 0, stream>>>(out, stats);
  }
}

// Round 13
// 39.938 us; speedup vs baseline: 1.0451x; 1.0451x over previous
//
#include <hip/hip_runtime.h>
#include <math.h>

constexpr int Bb = 4, Cc = 64, Hh = 256, Ww = 256;
constexpr int RR = 4;            // output rows per block
constexpr int CS = 4;            // channel split (16 ch per block)
constexpr int NSTRIP = Hh / RR;  // 64
constexpr int NPX = Bb * Hh * Ww;       // 262144 output pixels
constexpr int NPX4 = NPX / 4;           // 65536 float4s

#define LOG2E 1.44269504088896340736f
#define LN2   0.69314718055994530942f

__device__ __forceinline__ unsigned int fenc(float f) {
  unsigned int u = __float_as_uint(f);
  return (u & 0x80000000u) ? ~u : (u | 0x80000000u);
}
__device__ __forceinline__ float fdec(unsigned int k) {
  return __uint_as_float((k & 0x80000000u) ? (k ^ 0x80000000u) : ~k);
}

// entropy = ln(s) - ws/s, s = 3x3 box of e^v, ws = 3x3 box of v*e^v
// (shift-invariant softmax entropy; N(0,1) inputs so e^v safe in fp32).
// Normalization is affine-invariant, so raw channel sums are normalized.
//
// Grid: b(4) x strip(64) x cs(4) = 1024 blocks, block (64,8) -> 8192 waves.
// Each block: RR=4 output rows x 16 channels (2 per ty, rolled cc loop).
// Block 0 re-inits the 12 sync/stat words for the finish kernel (kernel
// boundary makes this visible — proven in r12).
// sync layout (uint): [0..3]=min keys (init 0xFFFFFFFF), [4..7]=max keys
// (init 0), [8..11]=arrival counters (init 0).
// NOTE: plain __launch_bounds__(512) only — min-waves hints spill (r6/r7).
template <int DST>
__global__ __launch_bounds__(512) void entropy_kernel(const float* __restrict__ x,
                                                      float* __restrict__ out,
                                                      unsigned int* __restrict__ sync) {
  const int bx = blockIdx.x;
  if (DST == 0 && bx == 0 && threadIdx.y == 0 && threadIdx.x < 12)
    sync[threadIdx.x] = (threadIdx.x < 4) ? 0xFFFFFFFFu : 0u;

  const int cs = bx & 3;
  const int strip = (bx >> 2) & (NSTRIP - 1);
  const int b = bx >> 8;
  const int r0 = strip * RR;
  const int tx = threadIdx.x;   // 0..63
  const int ty = threadIdx.y;   // 0..7
  const int w0 = tx * 4;

  const size_t planeStride = (size_t)Hh * Ww;
  const float* xb = x + ((size_t)b * Cc + cs * 16 + ty * 2) * planeStride + w0;

  float acc[RR][4];
#pragma unroll
  for (int o = 0; o < RR; ++o)
#pragma unroll
    for (int i = 0; i < 4; ++i) acc[o][i] = 0.f;

#pragma unroll 1
  for (int cc = 0; cc < 2; ++cc) {
    const float* plane = xb + (size_t)cc * planeStride;

    // Preload the RR+2 = 6 strip rows (6 outstanding dwordx4 loads).
    float4 v[RR + 2];
#pragma unroll
    for (int j = 0; j < RR + 2; ++j) {
      const int row = r0 - 1 + j;
      if (row >= 0 && row < Hh)
        v[j] = *reinterpret_cast<const float4*>(plane + (size_t)row * Ww);
      else
        v[j] = make_float4(0.f, 0.f, 0.f, 0.f);
    }

    float ha[3][4], hb[3][4];
#pragma unroll
    for (int j = 0; j < RR + 2; ++j) {
      const float* vp = &v[j].x;
      float a[4], bb4[4];
#pragma unroll
      for (int i = 0; i < 4; ++i) {
        float t = __builtin_amdgcn_exp2f(vp[i] * LOG2E);  // e^v
        a[i] = t;
        bb4[i] = vp[i] * t;                               // v * e^v
      }
      float la = __shfl_up(a[3], 1, 64);
      float lb = __shfl_up(bb4[3], 1, 64);
      float ra = __shfl_down(a[0], 1, 64);
      float rb = __shfl_down(bb4[0], 1, 64);
      la = (tx == 0) ? 1.f : la;   lb = (tx == 0) ? 0.f : lb;
      ra = (tx == 63) ? 1.f : ra;  rb = (tx == 63) ? 0.f : rb;
      const int s0 = j % 3;  // compile-time (loop unrolled)
      ha[s0][0] = la + a[0] + a[1];
      ha[s0][1] = a[0] + a[1] + a[2];
      ha[s0][2] = a[1] + a[2] + a[3];
      ha[s0][3] = a[2] + a[3] + ra;
      hb[s0][0] = lb + bb4[0] + bb4[1];
      hb[s0][1] = bb4[0] + bb4[1] + bb4[2];
      hb[s0][2] = bb4[1] + bb4[2] + bb4[3];
      hb[s0][3] = bb4[2] + bb4[3] + rb;
      if (j >= 2) {
        const int orow = j - 2;
#pragma unroll
        for (int i = 0; i < 4; ++i) {
          float s = ha[0][i] + ha[1][i] + ha[2][i];
          float w = hb[0][i] + hb[1][i] + hb[2][i];
          acc[orow][i] += LN2 * __builtin_amdgcn_logf(s) -
                          w * __builtin_amdgcn_rcpf(s);
        }
      }
    }
  }

  // Reduce the 8 ty groups (32 KiB LDS).
  __shared__ float red[8][RR][4][64];
#pragma unroll
  for (int o = 0; o < RR; ++o)
#pragma unroll
    for (int i = 0; i < 4; ++i) red[ty][o][i][tx] = acc[o][i];
  __syncthreads();
  if (ty < RR) {
    const int o = ty;
    const size_t px = (size_t)(b * Hh + r0 + o) * Ww + w0;
    float vsum[4];
#pragma unroll
    for (int i = 0; i < 4; ++i) {
      float t = 0.f;
#pragma unroll
      for (int g = 0; g < 8; ++g) t += red[g][o][i][tx];
      vsum[i] = t;
    }
    if (DST == 0) {
      *reinterpret_cast<float4*>(out + (size_t)cs * NPX + px) =
          make_float4(vsum[0], vsum[1], vsum[2], vsum[3]);
    } else {
#pragma unroll
      for (int i = 0; i < 4; ++i) atomicAdd(out + px + i, vsum[i]);
    }
  }
}

// Fused finish, atomic-only protocol (NO __threadfence — r12 showed device
// fences cost ~14us here): combine 4 partial planes in registers, fold the
// block's min/max into per-batch atomic words, bump the batch counter with
// RELEASE, spin-ACQUIRE until all 64 blocks of the batch arrived, then
// normalize from registers and write the final output.
// Grid 256 blocks x 256 threads; batch b = bx>>6.
__global__ __launch_bounds__(256) void finish_kernel(const float* __restrict__ pw,
                                                     float* __restrict__ e,
                                                     unsigned int* __restrict__ sync) {
  const int bx = blockIdx.x;
  const int b = bx >> 6;
  const int t = bx * 256 + threadIdx.x;

  float4 v0 = reinterpret_cast<const float4*>(pw)[t];
  float4 v1 = reinterpret_cast<const float4*>(pw + (size_t)NPX)[t];
  float4 v2 = reinterpret_cast<const float4*>(pw + 2 * (size_t)NPX)[t];
  float4 v3 = reinterpret_cast<const float4*>(pw + 3 * (size_t)NPX)[t];
  float4 v = make_float4(v0.x + v1.x + v2.x + v3.x, v0.y + v1.y + v2.y + v3.y,
                         v0.z + v1.z + v2.z + v3.z, v0.w + v1.w + v2.w + v3.w);

  // Block-level min/max.
  float mn = fminf(fminf(v.x, v.y), fminf(v.z, v.w));
  float mx = fmaxf(fmaxf(v.x, v.y), fmaxf(v.z, v.w));
#pragma unroll
  for (int off = 32; off > 0; off >>= 1) {
    mn = fminf(mn, __shfl_down(mn, off, 64));
    mx = fmaxf(mx, __shfl_down(mx, off, 64));
  }
  __shared__ float smn[4], smx[4];
  const int wave = threadIdx.x >> 6;
  if ((threadIdx.x & 63) == 0) { smn[wave] = mn; smx[wave] = mx; }
  __syncthreads();

  __shared__ float s_mn, s_inv;
  if (threadIdx.x == 0) {
    mn = fminf(fminf(smn[0], smn[1]), fminf(smn[2], smn[3]));
    mx = fmaxf(fmaxf(smx[0], smx[1]), fmaxf(smx[2], smx[3]));
    // Device-scope atomics are coherent at the agent point; no fence needed.
    atomicMin(&sync[b], fenc(mn));
    atomicMax(&sync[4 + b], fenc(mx));
    __hip_atomic_fetch_add(&sync[8 + b], 1u, __ATOMIC_RELEASE,
                           __HIP_MEMORY_SCOPE_AGENT);
    while (__hip_atomic_load(&sync[8 + b], __ATOMIC_ACQUIRE,
                             __HIP_MEMORY_SCOPE_AGENT) < 64u) {
      __builtin_amdgcn_s_sleep(1);
    }
    const float rmn = fdec(__hip_atomic_load(&sync[b], __ATOMIC_RELAXED,
                                             __HIP_MEMORY_SCOPE_AGENT));
    const float rmx = fdec(__hip_atomic_load(&sync[4 + b], __ATOMIC_RELAXED,
                                             __HIP_MEMORY_SCOPE_AGENT));
    s_mn = rmn;
    s_inv = 1.0f / fmaxf(rmx - rmn, 1e-6f);
  }
  __syncthreads();
  const float mnb = s_mn, inv = s_inv;
  v.x = (v.x - mnb) * inv;
  v.y = (v.y - mnb) * inv;
  v.z = (v.z - mnb) * inv;
  v.w = (v.w - mnb) * inv;
  reinterpret_cast<float4*>(e)[t] = v;
}

// Fallback path kernels (atomics + memset) — used only if ws is tiny.
__global__ __launch_bounds__(256) void minmax_atomic(const float* __restrict__ e,
                                                     unsigned int* __restrict__ stats) {
  const int bx = blockIdx.x;
  const int b = bx >> 6;
  const float4 v = reinterpret_cast<const float4*>(
      e + (size_t)b * Hh * Ww + (bx & 63) * 1024)[threadIdx.x];
  float mn = fminf(fminf(v.x, v.y), fminf(v.z, v.w));
  float mx = fmaxf(fmaxf(v.x, v.y), fmaxf(v.z, v.w));
#pragma unroll
  for (int off = 32; off > 0; off >>= 1) {
    mn = fminf(mn, __shfl_down(mn, off, 64));
    mx = fmaxf(mx, __shfl_down(mx, off, 64));
  }
  __shared__ float smn[4], smx[4];
  const int wave = threadIdx.x >> 6;
  if ((threadIdx.x & 63) == 0) { smn[wave] = mn; smx[wave] = mx; }
  __syncthreads();
  if (threadIdx.x == 0) {
    atomicMin(&stats[b], fenc(fminf(fminf(smn[0], smn[1]), fminf(smn[2], smn[3]))));
    atomicMax(&stats[4 + b], fenc(fmaxf(fmaxf(smx[0], smx[1]), fmaxf(smx[2], smx[3]))));
  }
}

__global__ __launch_bounds__(256) void norm_atomic(float* __restrict__ e,
                                                   const unsigned int* __restrict__ stats) {
  const int t = blockIdx.x * 256 + threadIdx.x;
  const int b = t >> 14;
  const float mn = fdec(stats[b]);
  const float mx = fdec(stats[4 + b]);
  const float inv = 1.0f / fmaxf(mx - mn, 1e-6f);
  float4 v = reinterpret_cast<float4*>(e)[t];
  v.x = (v.x - mn) * inv;
  v.y = (v.y - mn) * inv;
  v.z = (v.z - mn) * inv;
  v.w = (v.w - mn) * inv;
  reinterpret_cast<float4*>(e)[t] = v;
}

extern "C" void kernel_launch(void* const* d_in, const int* in_sizes, int n_in,
                              void* d_out, int out_size, void* d_ws, size_t ws_size,
                              hipStream_t stream) {
  const float* x = (const float*)d_in[0];
  float* out = (float*)d_out;

  // ws layout: pw[CS*NPX] | sync[12]
  const size_t ws_needed = ((size_t)CS * NPX + 16) * sizeof(float);
  if (ws_size >= ws_needed) {
    float* pw = (float*)d_ws;
    unsigned int* sync = (unsigned int*)(pw + (size_t)CS * NPX);
    entropy_kernel<0><<<dim3(Bb * NSTRIP * CS), dim3(64, 8), 0, stream>>>(x, pw, sync);
    finish_kernel<<<dim3(NPX4 / 256), dim3(256), 0, stream>>>(pw, out, sync);
  } else {
    unsigned int* stats = (unsigned int*)d_ws;  // 8 uints
    hipMemsetAsync(out, 0, (size_t)NPX * sizeof(float), stream);
    hipMemsetAsync(stats, 0xFF, 4 * sizeof(unsigned int), stream);
    hipMemsetAsync(stats + 4, 0x00, 4 * sizeof(unsigned int), stream);
    entropy_kernel<1><<<dim3(Bb * NSTRIP * CS), dim3(64, 8), 0, stream>>>(x, out, nullptr);
    minmax_atomic<<<dim3(Bb * 64), dim3(256), 0, stream>>>(out, stats);
    norm_atomic<<<dim3(NPX4 / 256), dim3(256), 0, stream>>>(out, stats);
  }
}

// Round 14
// 31.722 us; speedup vs baseline: 1.3158x; 1.2590x over previous
//
#include <hip/hip_runtime.h>
#include <math.h>

constexpr int Bb = 4, Cc = 64, Hh = 256, Ww = 256;
constexpr int RR = 4;             // output rows per block
constexpr int NW = 2;             // W slices (128 cols each)
constexpr int NSTRIP = Hh / RR;   // 64
constexpr int NBLK = Bb * NSTRIP * NW;  // 512 entropy blocks
constexpr int NPX = Bb * Hh * Ww;       // 262144 output pixels
constexpr int NPX4 = NPX / 4;

#define LOG2E 1.44269504088896340736f
#define LN2   0.69314718055994530942f

__device__ __forceinline__ unsigned int fenc(float f) {
  unsigned int u = __float_as_uint(f);
  return (u & 0x80000000u) ? ~u : (u | 0x80000000u);
}
__device__ __forceinline__ float fdec(unsigned int k) {
  return __uint_as_float((k & 0x80000000u) ? (k ^ 0x80000000u) : ~k);
}

// entropy = ln(s) - ws/s, s = 3x3 box of e^v, ws = 3x3 box of v*e^v
// (shift-invariant softmax entropy; zero-pad contributes a=1,b=0 = exp(0)).
// Normalization is affine-invariant -> raw channel sums are normalized.
//
// CS=1 / W-split geometry: block (64,16) = 16 waves; ty = 4 channels each
// (cc loop rolled), lane = 2 cols (float2), block = 128 cols x RR=4 rows,
// FULL 64-channel sum -> block-local min/max exists with no combine step.
// Grid: b(4) x strip(64) x wslice(2) = 512 blocks x 16 waves = 8192 waves.
// Cross-wslice halo: one boundary column per block, loaded lane-uniform
// (always a valid column: 127 or 128); image edges use the 1/0 constants.
// FB=0: block min/max -> pm[bx] non-atomic (no init needed).
// FB=1: fallback, atomicMin/Max into stats (pre-memset).
// NOTE: plain __launch_bounds__(1024) — min-waves hints spill (r6/r7).
template <int FB>
__global__ __launch_bounds__(1024) void entropy_kernel(const float* __restrict__ x,
                                                       float* __restrict__ e,
                                                       float* __restrict__ pm,
                                                       unsigned int* __restrict__ stats) {
  const int bx = blockIdx.x;
  const int wsl = bx & 1;
  const int strip = (bx >> 1) & (NSTRIP - 1);
  const int b = bx >> 7;
  const int r0 = strip * RR;
  const int tx = threadIdx.x;   // 0..63
  const int ty = threadIdx.y;   // 0..15
  const int c0 = wsl * 128;
  const int cw = c0 + tx * 2;
  const int edge_col = wsl ? (c0 - 1) : (c0 + 128);  // 127 or 128: always valid

  const size_t planeStride = (size_t)Hh * Ww;
  const float* xb = x + ((size_t)b * Cc + ty * 4) * planeStride;

  float acc[RR][2];
#pragma unroll
  for (int o = 0; o < RR; ++o) { acc[o][0] = 0.f; acc[o][1] = 0.f; }

#pragma unroll 1
  for (int cc = 0; cc < 4; ++cc) {
    const float* plane = xb + (size_t)cc * planeStride;

    float ha[3][2], hb[3][2];
#pragma unroll
    for (int j = 0; j < RR + 2; ++j) {
      const int row = r0 - 1 + j;
      float2 vv = make_float2(0.f, 0.f);
      float ev = 0.f;
      if (row >= 0 && row < Hh) {
        vv = *reinterpret_cast<const float2*>(plane + (size_t)row * Ww + cw);
        ev = plane[(size_t)row * Ww + edge_col];   // lane-uniform
      }
      float a0 = __builtin_amdgcn_exp2f(vv.x * LOG2E);
      float a1 = __builtin_amdgcn_exp2f(vv.y * LOG2E);
      float b0 = vv.x * a0, b1 = vv.y * a1;
      float ae = __builtin_amdgcn_exp2f(ev * LOG2E);
      float be = ev * ae;

      float la = __shfl_up(a1, 1, 64);
      float lb = __shfl_up(b1, 1, 64);
      float ra = __shfl_down(a0, 1, 64);
      float rb = __shfl_down(b0, 1, 64);
      if (tx == 0)  { la = wsl ? ae : 1.f;  lb = wsl ? be : 0.f; }
      if (tx == 63) { ra = wsl ? 1.f : ae;  rb = wsl ? 0.f : be; }

      const int s0 = j % 3;  // compile-time (loop unrolled)
      ha[s0][0] = la + a0 + a1;  ha[s0][1] = a0 + a1 + ra;
      hb[s0][0] = lb + b0 + b1;  hb[s0][1] = b0 + b1 + rb;

      if (j >= 2) {
        const int o = j - 2;
#pragma unroll
        for (int i = 0; i < 2; ++i) {
          float s = ha[0][i] + ha[1][i] + ha[2][i];
          float w = hb[0][i] + hb[1][i] + hb[2][i];
          acc[o][i] += LN2 * __builtin_amdgcn_logf(s) -
                       w * __builtin_amdgcn_rcpf(s);
        }
      }
    }
  }

  // Reduce the 16 ty channel groups (32 KiB LDS).
  __shared__ float red[16][RR][2][64];
#pragma unroll
  for (int o = 0; o < RR; ++o) {
    red[ty][o][0][tx] = acc[o][0];
    red[ty][o][1][tx] = acc[o][1];
  }
  __syncthreads();

  float mn = INFINITY, mx = -INFINITY;
  if (ty < RR) {
    const int o = ty;
    float v0 = 0.f, v1 = 0.f;
#pragma unroll
    for (int g = 0; g < 16; ++g) { v0 += red[g][o][0][tx]; v1 += red[g][o][1][tx]; }
    *reinterpret_cast<float2*>(e + (size_t)(b * Hh + r0 + o) * Ww + cw) =
        make_float2(v0, v1);
    mn = fminf(v0, v1);
    mx = fmaxf(v0, v1);
#pragma unroll
    for (int off = 32; off > 0; off >>= 1) {
      mn = fminf(mn, __shfl_down(mn, off, 64));
      mx = fmaxf(mx, __shfl_down(mx, off, 64));
    }
  }
  __shared__ float smn[RR], smx[RR];
  if (ty < RR && tx == 0) { smn[ty] = mn; smx[ty] = mx; }
  __syncthreads();
  if (ty == 0 && tx == 0) {
    mn = fminf(fminf(smn[0], smn[1]), fminf(smn[2], smn[3]));
    mx = fmaxf(fmaxf(smx[0], smx[1]), fmaxf(smx[2], smx[3]));
    if (FB == 0) {
      pm[bx] = mn;            // every slot written -> no init
      pm[NBLK + bx] = mx;
    } else {
      atomicMin(&stats[b], fenc(mn));
      atomicMax(&stats[4 + b], fenc(mx));
    }
  }
}

// Reduce this batch's 128 pm pairs in-block (no sync, no atomics), then
// normalize. Grid 256 blocks x 256 threads, one float4 per thread.
// Batch b = bx>>6; its entropy blocks are pm[b*128 .. b*128+127].
__global__ __launch_bounds__(256) void norm_ws(float* __restrict__ e,
                                               const float* __restrict__ pm) {
  const int bx = blockIdx.x;
  const int b = bx >> 6;
  const int k = threadIdx.x & 127;
  float mn = pm[b * 128 + k];
  float mx = pm[NBLK + b * 128 + k];
#pragma unroll
  for (int off = 32; off > 0; off >>= 1) {
    mn = fminf(mn, __shfl_down(mn, off, 64));
    mx = fmaxf(mx, __shfl_down(mx, off, 64));
  }
  __shared__ float smn[4], smx[4];
  const int wave = threadIdx.x >> 6;
  if ((threadIdx.x & 63) == 0) { smn[wave] = mn; smx[wave] = mx; }
  __syncthreads();
  mn = fminf(fminf(smn[0], smn[1]), fminf(smn[2], smn[3]));
  mx = fmaxf(fmaxf(smx[0], smx[1]), fmaxf(smx[2], smx[3]));
  const float inv = 1.0f / fmaxf(mx - mn, 1e-6f);

  const int t = bx * 256 + threadIdx.x;
  float4 v = reinterpret_cast<float4*>(e)[t];
  v.x = (v.x - mn) * inv;
  v.y = (v.y - mn) * inv;
  v.z = (v.z - mn) * inv;
  v.w = (v.w - mn) * inv;
  reinterpret_cast<float4*>(e)[t] = v;
}

// Fallback normalize from atomic stats.
__global__ __launch_bounds__(256) void norm_atomic(float* __restrict__ e,
                                                   const unsigned int* __restrict__ stats) {
  const int t = blockIdx.x * 256 + threadIdx.x;
  const int b = t >> 14;
  const float mn = fdec(stats[b]);
  const float mx = fdec(stats[4 + b]);
  const float inv = 1.0f / fmaxf(mx - mn, 1e-6f);
  float4 v = reinterpret_cast<float4*>(e)[t];
  v.x = (v.x - mn) * inv;
  v.y = (v.y - mn) * inv;
  v.z = (v.z - mn) * inv;
  v.w = (v.w - mn) * inv;
  reinterpret_cast<float4*>(e)[t] = v;
}

extern "C" void kernel_launch(void* const* d_in, const int* in_sizes, int n_in,
                              void* d_out, int out_size, void* d_ws, size_t ws_size,
                              hipStream_t stream) {
  const float* x = (const float*)d_in[0];
  float* out = (float*)d_out;

  const size_t ws_needed = (size_t)(2 * NBLK) * sizeof(float);  // 4 KB
  if (ws_size >= ws_needed) {
    float* pm = (float*)d_ws;  // [NBLK min][NBLK max]
    entropy_kernel<0><<<dim3(NBLK), dim3(64, 16), 0, stream>>>(x, out, pm, nullptr);
    norm_ws<<<dim3(NPX4 / 256), dim3(256), 0, stream>>>(out, pm);
  } else {
    unsigned int* stats = (unsigned int*)d_ws;  // 8 uints
    hipMemsetAsync(stats, 0xFF, 4 * sizeof(unsigned int), stream);
    hipMemsetAsync(stats + 4, 0x00, 4 * sizeof(unsigned int), stream);
    entropy_kernel<1><<<dim3(NBLK), dim3(64, 16), 0, stream>>>(x, out, nullptr, stats);
    norm_atomic<<<dim3(NPX4 / 256), dim3(256), 0, stream>>>(out, stats);
  }
}